// Round 7
// baseline (147.393 us; speedup 1.0000x reference)
//
#include <hip/hip_runtime.h>

// FeatureMatchSimpleLoss: B=128, P=512, D=384, GAMMA=20, LAMBDA_INV=25
// R7: bf16 MFMA, symmetric upper-tri tiling, DEPTH-2 pipeline: 3 LDS buffers,
// one s_barrier per k-step, counted vmcnt(4) keeps 2 tiles in flight so
// L3/HBM load latency (~500-900cy) hides under 2 compute phases x 3 blocks/CU.
//   fm_convert:    z(fp32) -> z bf16 (RNE)
//   fm_gemm:       per (b, upper-tri 128x128 tile), fused masked row+col argmax
//   fm_topk_local: wave-level (64-thr blocks) combine + local top-20, no barriers
//   fm_final:      wave-level merge of 1280 -> top-20 -> best-j -> loss + avg

#define NB 128
#define NP 512
#define ND 384
#define NGAMMA 20
#define NKS 12   // 384 / 32 k-steps

typedef __attribute__((ext_vector_type(8))) short short8;
typedef __attribute__((ext_vector_type(4))) float f32x4;

__device__ __forceinline__ unsigned short f2bf(float f) {
    unsigned int u = __float_as_uint(f);
    u += 0x7fffu + ((u >> 16) & 1u);   // RNE
    return (unsigned short)(u >> 16);
}

__device__ __forceinline__ void gload16(const void* gptr, void* lptr) {
    __builtin_amdgcn_global_load_lds(
        (const __attribute__((address_space(1))) void*)gptr,
        (__attribute__((address_space(3))) void*)lptr, 16, 0, 0);
}

// ---- convert: 8 floats/thread -> 8 bf16 ----
__global__ __launch_bounds__(256) void fm_convert(
    const float* __restrict__ z, unsigned short* __restrict__ zhi)
{
    size_t i = (size_t)blockIdx.x * 256 + threadIdx.x;
    const float4* zp = (const float4*)z + i * 2;
    float4 v0 = zp[0], v1 = zp[1];
    float f[8] = {v0.x, v0.y, v0.z, v0.w, v1.x, v1.y, v1.z, v1.w};
    short8 s;
#pragma unroll
    for (int j = 0; j < 8; ++j) s[j] = (short)f2bf(f[j]);
    *(short8*)&zhi[i * 8] = s;
}

// ---- MFMA GEMM, depth-2 / 3-buffer / 1-barrier-per-step pipeline ----
__global__ __launch_bounds__(256, 3) void fm_gemm(
    const unsigned short* __restrict__ zhi, const int* __restrict__ view,
    float* __restrict__ pval, int* __restrict__ pidx)
{
    // [buf][kg][row][8] bf16: gload_lds dest linear (uniform base + lane*16);
    // ds_read_b128 frag reads conflict-free (measured 0 since R2).
    __shared__ __align__(16) unsigned short Ah[3][4][128][8];   // 24 KB
    __shared__ __align__(16) unsigned short Bh[3][4][128][8];   // 24 KB
    __shared__ int vs[NP];                                      //  2 KB
    // epilogue scratch aliased onto Ah[0] (dead after k-loop: steps 9/10/11
    // read bufs 0/1/2; any wave past step-11's barrier implies all waves
    // finished step 9, so nobody reads Ah[0] while scratch is written).
    float* lsv = (float*)&Ah[0][0][0][0];        // [2][2][64]
    int*   lsi = (int*)lsv + 256;
    float* lqv = (float*)((int*)lsv + 512);
    int*   lqi = (int*)lsv + 768;

    const int tid  = threadIdx.x;
    const int lane = tid & 63;
    const int wid  = tid >> 6;
    const int wr   = wid >> 1, wc = wid & 1;
    const int g    = lane >> 4, r = lane & 15;

    // XCD swizzle (1280 % 8 == 0 -> bijective): each XCD gets 16 whole batches
    const int bid  = blockIdx.x;
    const int gidx = (bid & 7) * 160 + (bid >> 3);   // 0..1279
    const int b    = gidx / 10;
    const int t    = gidx % 10;
    int tr, tc;
    if (t < 4)      { tr = 0; tc = t; }
    else if (t < 7) { tr = 1; tc = t - 3; }
    else if (t < 9) { tr = 2; tc = t - 5; }
    else            { tr = 3; tc = 3; }
    const bool diag = (tr == tc);
    const int p0 = tr * 128, q0 = tc * 128;

    vs[tid]       = view[tid];
    vs[tid + 256] = view[tid + 256];
    __builtin_amdgcn_sched_barrier(0);   // vs loads issue before staging

    const size_t zb = (size_t)b * NP * ND;

    f32x4 acc[4][4];
#pragma unroll
    for (int mi = 0; mi < 4; ++mi)
#pragma unroll
        for (int ni = 0; ni < 4; ++ni) acc[mi][ni] = (f32x4){0.f, 0.f, 0.f, 0.f};

    // stage one 32-k tile: 8 chunks of 1KB per matrix; wave wid does chunks
    // {2wid, 2wid+1} of A and of B (diag stages B redundantly -> uniform path)
#define STAGE(BUF, KT)                                                           \
    do {                                                                         \
        _Pragma("unroll")                                                        \
        for (int i = 0; i < 2; ++i) {                                            \
            const int c_  = wid * 2 + i;                                         \
            const int kg_ = c_ >> 1;                                             \
            const int rb_ = (c_ & 1) * 64;                                       \
            gload16(zhi + zb + (size_t)(p0 + rb_ + lane) * ND + (KT) * 32 + kg_ * 8, \
                    &Ah[BUF][kg_][rb_][0]);                                      \
            gload16(zhi + zb + (size_t)(q0 + rb_ + lane) * ND + (KT) * 32 + kg_ * 8, \
                    &Bh[BUF][kg_][rb_][0]);                                      \
        }                                                                        \
    } while (0)

#define COMPUTE(BUF)                                                             \
    do {                                                                         \
        short8 ah_[4], bh_[4];                                                   \
        _Pragma("unroll")                                                        \
        for (int mi = 0; mi < 4; ++mi)                                           \
            ah_[mi] = *(const short8*)&Ah[BUF][g][wr * 64 + mi * 16 + r][0];     \
        _Pragma("unroll")                                                        \
        for (int ni = 0; ni < 4; ++ni)                                           \
            bh_[ni] = *(const short8*)&Bh[BUF][g][wc * 64 + ni * 16 + r][0];     \
        _Pragma("unroll")                                                        \
        for (int mi = 0; mi < 4; ++mi)                                           \
            _Pragma("unroll")                                                    \
            for (int ni = 0; ni < 4; ++ni)                                       \
                acc[mi][ni] = __builtin_amdgcn_mfma_f32_16x16x32_bf16(           \
                    ah_[mi], bh_[ni], acc[mi][ni], 0, 0, 0);                     \
    } while (0)

    STAGE(0, 0);
    STAGE(1, 1);
#pragma unroll
    for (int kt = 0; kt < NKS; ++kt) {
        // steady state at entry: tiles kt (4 loads) + kt+1 (4 loads) in flight.
        // vmcnt(4) -> tile kt landed (issued 2 steps ago = full latency cover).
        if (kt < NKS - 1) asm volatile("s_waitcnt vmcnt(4)" ::: "memory");
        else              asm volatile("s_waitcnt vmcnt(0)" ::: "memory");
        __builtin_amdgcn_s_barrier();          // all waves: tile kt resident,
                                               // and compute(kt-1) done -> the
                                               // buffer STAGE will write is free
        __builtin_amdgcn_sched_barrier(0);
        if (kt + 2 < NKS) STAGE((kt + 2) % 3, kt + 2);
        __builtin_amdgcn_sched_barrier(0);     // stage issues before compute
        COMPUTE(kt % 3);
    }
#undef STAGE
#undef COMPUTE

    // ---- row-side: per row p, masked max/argmax over this tile's 128 cols ----
    // C/D layout: col = lane&15 (r), row = (lane>>4)*4 + j (g,j)
#pragma unroll
    for (int mi = 0; mi < 4; ++mi) {
#pragma unroll
        for (int j = 0; j < 4; ++j) {
            const int prow = p0 + wr * 64 + mi * 16 + g * 4 + j;
            const int rv = vs[prow];
            float bv = -2.0f; int bq = 0;
#pragma unroll
            for (int ni = 0; ni < 4; ++ni) {   // ascending q; strict > keeps smallest
                const int q = q0 + wc * 64 + ni * 16 + r;
                const float v = (vs[q] != rv) ? acc[mi][ni][j] : -1.0f;
                if (v > bv) { bv = v; bq = q; }
            }
#pragma unroll
            for (int off = 1; off < 16; off <<= 1) {   // reduce over col-lanes
                const float ov = __shfl_xor(bv, off);
                const int   oq = __shfl_xor(bq, off);
                if (ov > bv || (ov == bv && oq < bq)) { bv = ov; bq = oq; }
            }
            if (r == 0) {
                lsv[(wr * 2 + wc) * 64 + mi * 16 + g * 4 + j] = bv;
                lsi[(wr * 2 + wc) * 64 + mi * 16 + g * 4 + j] = bq;
            }
        }
    }
    // ---- col-side (off-diag only): per col q, masked max/argmax over 128 rows ----
    if (!diag) {
#pragma unroll
        for (int ni = 0; ni < 4; ++ni) {
            const int q = q0 + wc * 64 + ni * 16 + r;
            const int qv = vs[q];
            float bv = -2.0f; int bp = 0;
#pragma unroll
            for (int mi = 0; mi < 4; ++mi)
#pragma unroll
                for (int j = 0; j < 4; ++j) {   // ascending p within fixed g
                    const int prow = p0 + wr * 64 + mi * 16 + g * 4 + j;
                    const float v = (vs[prow] != qv) ? acc[mi][ni][j] : -1.0f;
                    if (v > bv) { bv = v; bp = prow; }
                }
#pragma unroll
            for (int off = 16; off < 64; off <<= 1) {   // reduce over g groups
                const float ov = __shfl_xor(bv, off);
                const int   op = __shfl_xor(bp, off);
                if (ov > bv || (ov == bv && op < bp)) { bv = ov; bp = op; }
            }
            if (g == 0) {
                lqv[(wc * 2 + wr) * 64 + ni * 16 + r] = bv;
                lqi[(wc * 2 + wr) * 64 + ni * 16 + r] = bp;
            }
        }
    }
    __syncthreads();
    if (tid < 128) {
        const int half = tid >> 6, row = tid & 63;
        {
            float v0 = lsv[(half * 2 + 0) * 64 + row]; int i0 = lsi[(half * 2 + 0) * 64 + row];
            const float v1 = lsv[(half * 2 + 1) * 64 + row]; const int i1 = lsi[(half * 2 + 1) * 64 + row];
            if (v1 > v0) { v0 = v1; i0 = i1; }   // tie keeps wc=0 (smaller q)
            const int p = p0 + half * 64 + row;
            pval[((size_t)b * NP + p) * 4 + tc] = v0;
            pidx[((size_t)b * NP + p) * 4 + tc] = i0;
        }
        if (!diag) {
            float v0 = lqv[(half * 2 + 0) * 64 + row]; int i0 = lqi[(half * 2 + 0) * 64 + row];
            const float v1 = lqv[(half * 2 + 1) * 64 + row]; const int i1 = lqi[(half * 2 + 1) * 64 + row];
            if (v1 > v0) { v0 = v1; i0 = i1; }   // tie keeps wr=0 (smaller p)
            const int q = q0 + half * 64 + row;
            pval[((size_t)b * NP + q) * 4 + tr] = v0;
            pidx[((size_t)b * NP + q) * 4 + tr] = i0;
        }
    }
}

// ---- Phase 2a: wave-level combine + local top-20 over 1024 anchors ----
__global__ __launch_bounds__(64) void fm_topk_local(
    const float* __restrict__ pval, float* __restrict__ cval, int* __restrict__ cidx)
{
    const int lane = threadIdx.x;
    const int base = blockIdx.x * 1024;
    float v[16]; int id[16];
#pragma unroll
    for (int i = 0; i < 16; ++i) {
        const int a = base + i * 64 + lane;
        const float4 pv = ((const float4*)pval)[a];
        float bv = pv.x;                       // ascending c; strict > keeps first
        if (pv.y > bv) bv = pv.y;
        if (pv.z > bv) bv = pv.z;
        if (pv.w > bv) bv = pv.w;
        v[i] = bv; id[i] = a;
    }
    for (int it = 0; it < NGAMMA; ++it) {
        float bv = v[0]; int bi = id[0];
#pragma unroll
        for (int i = 1; i < 16; ++i)
            if (v[i] > bv || (v[i] == bv && id[i] < bi)) { bv = v[i]; bi = id[i]; }
#pragma unroll
        for (int off = 1; off < 64; off <<= 1) {
            const float ov = __shfl_xor(bv, off);
            const int   oi = __shfl_xor(bi, off);
            if (ov > bv || (ov == bv && oi < bi)) { bv = ov; bi = oi; }
        }
        if (lane == 0) {
            cval[blockIdx.x * NGAMMA + it] = bv;
            cidx[blockIdx.x * NGAMMA + it] = bi;
        }
#pragma unroll
        for (int i = 0; i < 16; ++i) if (id[i] == bi) v[i] = -1e30f;
    }
}

// ---- Phase 2b: wave-level merge 1280 -> top-20 -> best-j -> loss + avg ----
__global__ __launch_bounds__(256) void fm_final(
    const float* __restrict__ cval, const int* __restrict__ cidx,
    const float* __restrict__ pval, const int* __restrict__ pidx,
    const float* __restrict__ z, float* __restrict__ out)
{
    __shared__ int sel[NGAMMA];
    __shared__ int selj[NGAMMA];
    __shared__ float red[4];

    const int t = threadIdx.x;
    const int lane = t & 63, w = t >> 6;
    float ssum = 0.f;

    if (w == 0) {
        float v[20]; int id[20];
#pragma unroll
        for (int i = 0; i < 20; ++i) {
            const int e = i * 64 + lane;
            v[i] = cval[e]; id[i] = cidx[e];
        }
        for (int it = 0; it < NGAMMA; ++it) {
            float bv = v[0]; int bi = id[0];
#pragma unroll
            for (int i = 1; i < 20; ++i)
                if (v[i] > bv || (v[i] == bv && id[i] < bi)) { bv = v[i]; bi = id[i]; }
#pragma unroll
            for (int off = 1; off < 64; off <<= 1) {
                const float ov = __shfl_xor(bv, off);
                const int   oi = __shfl_xor(bi, off);
                if (ov > bv || (ov == bv && oi < bi)) { bv = ov; bi = oi; }
            }
            if (lane == 0) sel[it] = bi;
            ssum += bv;
#pragma unroll
            for (int i = 0; i < 20; ++i) if (id[i] == bi) v[i] = -1e30f;
        }
        // best-j for the 20 selected anchors (argmax over 4 partials)
        if (lane < NGAMMA) {
            const int a = sel[lane];   // written by lane0; same-wave LDS ordered
            const float4 pv = ((const float4*)pval)[a];
            float bv = pv.x; int bc = 0;       // ascending c = ascending q-block
            if (pv.y > bv) { bv = pv.y; bc = 1; }
            if (pv.z > bv) { bv = pv.z; bc = 2; }
            if (pv.w > bv) { bv = pv.w; bc = 3; }
            selj[lane] = ((a >> 9) << 9) + pidx[(size_t)a * 4 + bc];
        }
    }
    __syncthreads();

    // loss = 25 * mean((z1 - z2)^2) over 20 x 384 (exact fp32 z)
    float acc = 0.f;
    for (int pr = 0; pr < NGAMMA; ++pr) {
        const int a = sel[pr];
        const int j = selj[pr];
        const float* za = z + (size_t)a * ND;
        const float* zj = z + (size_t)j * ND;
        for (int d = t; d < ND; d += 256) {
            const float df = za[d] - zj[d];
            acc = fmaf(df, df, acc);
        }
    }
#pragma unroll
    for (int off = 1; off < 64; off <<= 1) acc += __shfl_xor(acc, off);
    if (lane == 0) red[w] = acc;
    __syncthreads();
    if (t == 0) {
        const float tot = red[0] + red[1] + red[2] + red[3];
        out[0] = 25.0f * tot / (float)(NGAMMA * ND);
        out[1] = ssum / (float)NGAMMA;   // t==0 is lane0 of wave0: has ssum
    }
}

extern "C" void kernel_launch(void* const* d_in, const int* in_sizes, int n_in,
                              void* d_out, int out_size, void* d_ws, size_t ws_size,
                              hipStream_t stream)
{
    const float* z    = (const float*)d_in[0];
    const int*   view = (const int*)d_in[1];
    float*       out  = (float*)d_out;
    char* ws = (char*)d_ws;

    // layout: zhi 48MB | pval 1MB | pidx 1MB | cval | cidx
    const size_t zhi_off  = 0;
    const size_t pval_off = (size_t)NB * NP * ND * 2;
    const size_t pidx_off = pval_off + (size_t)NB * NP * 4 * 4;
    const size_t cval_off = pidx_off + (size_t)NB * NP * 4 * 4;
    const size_t cidx_off = cval_off + 64 * NGAMMA * 4;

    unsigned short* zhi = (unsigned short*)(ws + zhi_off);
    float* pval = (float*)(ws + pval_off);
    int*   pidx = (int*)(ws + pidx_off);
    float* cval = (float*)(ws + cval_off);
    int*   cidx = (int*)(ws + cidx_off);

    fm_convert<<<(NB * NP * ND) / (8 * 256), 256, 0, stream>>>(z, zhi);
    fm_gemm<<<NB * 10, 256, 0, stream>>>(zhi, view, pval, pidx);
    fm_topk_local<<<(NB * NP) / 1024, 64, 0, stream>>>(pval, cval, cidx);
    fm_final<<<1, 256, 0, stream>>>(cval, cidx, pval, pidx, z, out);
}

// Round 8
// 134.521 us; speedup vs baseline: 1.0957x; 1.0957x over previous
//
#include <hip/hip_runtime.h>

// FeatureMatchSimpleLoss: B=128, P=512, D=384, GAMMA=20, LAMBDA_INV=25
// R8: bf16 MFMA, symmetric upper-tri tiling, depth-2 pipeline (3 LDS bufs,
// 1 barrier/step, counted vmcnt) + COALESCED STAGING: convert pre-tiles z
// into zt[b][kt][kg][p][8] bf16 so every global_load_lds chunk is a
// contiguous 1KB (lane*16B) matching the linear LDS dest. R7's staging read
// 64 cache lines per instruction (768B lane stride) -> ~4 TB/s wall.
//   fm_convert:    z(fp32) -> zt tiled bf16 (LDS transpose, coalesced both sides)
//   fm_gemm:       per (b, upper-tri 128x128 tile), fused masked row+col argmax
//   fm_topk_local: wave-level combine + local top-20 (64-thr blocks)
//   fm_final:      wave-level merge 1280 -> top-20 -> best-j -> loss + avg

#define NB 128
#define NP 512
#define ND 384
#define NGAMMA 20
#define NKS 12   // 384 / 32 k-steps

typedef __attribute__((ext_vector_type(8))) short short8;
typedef __attribute__((ext_vector_type(4))) float f32x4;

__device__ __forceinline__ unsigned short f2bf(float f) {
    unsigned int u = __float_as_uint(f);
    u += 0x7fffu + ((u >> 16) & 1u);   // RNE
    return (unsigned short)(u >> 16);
}

__device__ __forceinline__ void gload16(const void* gptr, void* lptr) {
    __builtin_amdgcn_global_load_lds(
        (const __attribute__((address_space(1))) void*)gptr,
        (__attribute__((address_space(3))) void*)lptr, 16, 0, 0);
}

// ---- convert+tile: z fp32 row-major -> zt[b][kt][kg][p 0..511][8] bf16 ----
// Each block: one (b, kt, 128-row band). LDS transpose keeps both global
// sides coalesced. grid = NB * NKS * 4.
__global__ __launch_bounds__(256) void fm_convert(
    const float* __restrict__ z, unsigned short* __restrict__ zt)
{
    __shared__ float ls[128][36];   // pad 36: float4 rows 16B-aligned

    const int tid  = threadIdx.x;
    const int bid  = blockIdx.x;
    const int b    = bid / (NKS * 4);
    const int rem  = bid % (NKS * 4);
    const int kt   = rem >> 2;
    const int pblk = rem & 3;

    // load 128 rows x 32 cols fp32 (coalesced: 8 float4-lanes per row)
    const float* zsrc = z + ((size_t)b * NP + pblk * 128) * ND + kt * 32;
#pragma unroll
    for (int i = 0; i < 4; ++i) {
        const int f   = tid + i * 256;   // 0..1023 float4 ids
        const int row = f >> 3, c4 = f & 7;
        const float4 v = *(const float4*)(zsrc + (size_t)row * ND + c4 * 4);
        *(float4*)&ls[row][c4 * 4] = v;
    }
    __syncthreads();

    // write out: wave = kg plane; lane = row. 16B/lane contiguous -> 1KB/wave.
    const int kg = tid >> 6, lane = tid & 63;
    unsigned short* dst = zt + (((size_t)b * NKS + kt) * 4 + kg) * 4096
                             + (size_t)pblk * 128 * 8;
#pragma unroll
    for (int it = 0; it < 2; ++it) {
        const int row = it * 64 + lane;
        const float4 v0 = *(const float4*)&ls[row][kg * 8];
        const float4 v1 = *(const float4*)&ls[row][kg * 8 + 4];
        short8 s;
        s[0] = (short)f2bf(v0.x); s[1] = (short)f2bf(v0.y);
        s[2] = (short)f2bf(v0.z); s[3] = (short)f2bf(v0.w);
        s[4] = (short)f2bf(v1.x); s[5] = (short)f2bf(v1.y);
        s[6] = (short)f2bf(v1.z); s[7] = (short)f2bf(v1.w);
        *(short8*)(dst + (size_t)row * 8) = s;
    }
}

// ---- MFMA GEMM, depth-2 / 3-buffer / 1-barrier-per-step, coalesced staging ----
__global__ __launch_bounds__(256, 3) void fm_gemm(
    const unsigned short* __restrict__ zt, const int* __restrict__ view,
    float* __restrict__ pval, int* __restrict__ pidx)
{
    // [buf][kg][row][8] bf16: gload_lds dest linear (uniform base + lane*16);
    // ds_read_b128 frag reads conflict-free (measured 0 since R2).
    __shared__ __align__(16) unsigned short Ah[3][4][128][8];   // 24 KB
    __shared__ __align__(16) unsigned short Bh[3][4][128][8];   // 24 KB
    __shared__ int vs[NP];                                      //  2 KB
    // epilogue scratch aliased onto Ah[0] (dead: the kt=11 barrier implies all
    // waves finished COMPUTE(9), the last reader of buf 0).
    float* lsv = (float*)&Ah[0][0][0][0];        // [2][2][64]
    int*   lsi = (int*)lsv + 256;
    float* lqv = (float*)((int*)lsv + 512);
    int*   lqi = (int*)lsv + 768;

    const int tid  = threadIdx.x;
    const int lane = tid & 63;
    const int wid  = tid >> 6;
    const int wr   = wid >> 1, wc = wid & 1;
    const int g    = lane >> 4, r = lane & 15;

    // XCD swizzle (1280 % 8 == 0 -> bijective): each XCD gets 16 whole batches
    const int bid  = blockIdx.x;
    const int gidx = (bid & 7) * 160 + (bid >> 3);   // 0..1279
    const int b    = gidx / 10;
    const int t    = gidx % 10;
    int tr, tc;
    if (t < 4)      { tr = 0; tc = t; }
    else if (t < 7) { tr = 1; tc = t - 3; }
    else if (t < 9) { tr = 2; tc = t - 5; }
    else            { tr = 3; tc = 3; }
    const bool diag = (tr == tc);
    const int p0 = tr * 128, q0 = tc * 128;

    vs[tid]       = view[tid];
    vs[tid + 256] = view[tid + 256];
    __builtin_amdgcn_sched_barrier(0);   // vs loads issue before staging

    f32x4 acc[4][4];
#pragma unroll
    for (int mi = 0; mi < 4; ++mi)
#pragma unroll
        for (int ni = 0; ni < 4; ++ni) acc[mi][ni] = (f32x4){0.f, 0.f, 0.f, 0.f};

    // stage one 32-k tile: 8 contiguous-1KB chunks per matrix; wave wid does
    // chunks {2wid, 2wid+1} of A and of B (diag stages B redundantly; L2-hot).
#define STAGE(BUF, KT)                                                           \
    do {                                                                         \
        _Pragma("unroll")                                                        \
        for (int i = 0; i < 2; ++i) {                                            \
            const int c_  = wid * 2 + i;                                         \
            const int kg_ = c_ >> 1;                                             \
            const int rb_ = (c_ & 1) * 64;                                       \
            const size_t pl_ = (((size_t)b * NKS + (KT)) * 4 + kg_) * 4096;      \
            gload16(zt + pl_ + (size_t)(p0 + rb_ + lane) * 8,                    \
                    &Ah[BUF][kg_][rb_][0]);                                      \
            gload16(zt + pl_ + (size_t)(q0 + rb_ + lane) * 8,                    \
                    &Bh[BUF][kg_][rb_][0]);                                      \
        }                                                                        \
    } while (0)

#define COMPUTE(BUF)                                                             \
    do {                                                                         \
        short8 ah_[4], bh_[4];                                                   \
        _Pragma("unroll")                                                        \
        for (int mi = 0; mi < 4; ++mi)                                           \
            ah_[mi] = *(const short8*)&Ah[BUF][g][wr * 64 + mi * 16 + r][0];     \
        _Pragma("unroll")                                                        \
        for (int ni = 0; ni < 4; ++ni)                                           \
            bh_[ni] = *(const short8*)&Bh[BUF][g][wc * 64 + ni * 16 + r][0];     \
        _Pragma("unroll")                                                        \
        for (int mi = 0; mi < 4; ++mi)                                           \
            _Pragma("unroll")                                                    \
            for (int ni = 0; ni < 4; ++ni)                                       \
                acc[mi][ni] = __builtin_amdgcn_mfma_f32_16x16x32_bf16(           \
                    ah_[mi], bh_[ni], acc[mi][ni], 0, 0, 0);                     \
    } while (0)

    STAGE(0, 0);
    STAGE(1, 1);
#pragma unroll
    for (int kt = 0; kt < NKS; ++kt) {
        // steady state at entry: tiles kt (4 loads) + kt+1 (4) in flight.
        // vmcnt(4) -> tile kt (issued 2 steps ago) landed.
        if (kt < NKS - 1) asm volatile("s_waitcnt vmcnt(4)" ::: "memory");
        else              asm volatile("s_waitcnt vmcnt(0)" ::: "memory");
        __builtin_amdgcn_s_barrier();          // tile kt resident everywhere;
                                               // compute(kt-1) done -> STAGE's
                                               // target buffer is free
        __builtin_amdgcn_sched_barrier(0);
        if (kt + 2 < NKS) STAGE((kt + 2) % 3, kt + 2);
        __builtin_amdgcn_sched_barrier(0);     // stage issues before compute
        COMPUTE(kt % 3);
    }
#undef STAGE
#undef COMPUTE

    // ---- row-side: per row p, masked max/argmax over this tile's 128 cols ----
    // C/D layout: col = lane&15 (r), row = (lane>>4)*4 + j (g,j)
#pragma unroll
    for (int mi = 0; mi < 4; ++mi) {
#pragma unroll
        for (int j = 0; j < 4; ++j) {
            const int prow = p0 + wr * 64 + mi * 16 + g * 4 + j;
            const int rv = vs[prow];
            float bv = -2.0f; int bq = 0;
#pragma unroll
            for (int ni = 0; ni < 4; ++ni) {   // ascending q; strict > keeps smallest
                const int q = q0 + wc * 64 + ni * 16 + r;
                const float v = (vs[q] != rv) ? acc[mi][ni][j] : -1.0f;
                if (v > bv) { bv = v; bq = q; }
            }
#pragma unroll
            for (int off = 1; off < 16; off <<= 1) {   // reduce over col-lanes
                const float ov = __shfl_xor(bv, off);
                const int   oq = __shfl_xor(bq, off);
                if (ov > bv || (ov == bv && oq < bq)) { bv = ov; bq = oq; }
            }
            if (r == 0) {
                lsv[(wr * 2 + wc) * 64 + mi * 16 + g * 4 + j] = bv;
                lsi[(wr * 2 + wc) * 64 + mi * 16 + g * 4 + j] = bq;
            }
        }
    }
    // ---- col-side (off-diag only): per col q, masked max/argmax over 128 rows ----
    if (!diag) {
#pragma unroll
        for (int ni = 0; ni < 4; ++ni) {
            const int q = q0 + wc * 64 + ni * 16 + r;
            const int qv = vs[q];
            float bv = -2.0f; int bp = 0;
#pragma unroll
            for (int mi = 0; mi < 4; ++mi)
#pragma unroll
                for (int j = 0; j < 4; ++j) {   // ascending p within fixed g
                    const int prow = p0 + wr * 64 + mi * 16 + g * 4 + j;
                    const float v = (vs[prow] != qv) ? acc[mi][ni][j] : -1.0f;
                    if (v > bv) { bv = v; bp = prow; }
                }
#pragma unroll
            for (int off = 16; off < 64; off <<= 1) {   // reduce over g groups
                const float ov = __shfl_xor(bv, off);
                const int   op = __shfl_xor(bp, off);
                if (ov > bv || (ov == bv && op < bp)) { bv = ov; bp = op; }
            }
            if (g == 0) {
                lqv[(wc * 2 + wr) * 64 + ni * 16 + r] = bv;
                lqi[(wc * 2 + wr) * 64 + ni * 16 + r] = bp;
            }
        }
    }
    __syncthreads();
    if (tid < 128) {
        const int half = tid >> 6, row = tid & 63;
        {
            float v0 = lsv[(half * 2 + 0) * 64 + row]; int i0 = lsi[(half * 2 + 0) * 64 + row];
            const float v1 = lsv[(half * 2 + 1) * 64 + row]; const int i1 = lsi[(half * 2 + 1) * 64 + row];
            if (v1 > v0) { v0 = v1; i0 = i1; }   // tie keeps wc=0 (smaller q)
            const int p = p0 + half * 64 + row;
            pval[((size_t)b * NP + p) * 4 + tc] = v0;
            pidx[((size_t)b * NP + p) * 4 + tc] = i0;
        }
        if (!diag) {
            float v0 = lqv[(half * 2 + 0) * 64 + row]; int i0 = lqi[(half * 2 + 0) * 64 + row];
            const float v1 = lqv[(half * 2 + 1) * 64 + row]; const int i1 = lqi[(half * 2 + 1) * 64 + row];
            if (v1 > v0) { v0 = v1; i0 = i1; }   // tie keeps wr=0 (smaller p)
            const int q = q0 + half * 64 + row;
            pval[((size_t)b * NP + q) * 4 + tr] = v0;
            pidx[((size_t)b * NP + q) * 4 + tr] = i0;
        }
    }
}

// ---- Phase 2a: wave-level combine + local top-20 over 1024 anchors ----
__global__ __launch_bounds__(64) void fm_topk_local(
    const float* __restrict__ pval, float* __restrict__ cval, int* __restrict__ cidx)
{
    const int lane = threadIdx.x;
    const int base = blockIdx.x * 1024;
    float v[16]; int id[16];
#pragma unroll
    for (int i = 0; i < 16; ++i) {
        const int a = base + i * 64 + lane;
        const float4 pv = ((const float4*)pval)[a];
        float bv = pv.x;                       // ascending c; strict > keeps first
        if (pv.y > bv) bv = pv.y;
        if (pv.z > bv) bv = pv.z;
        if (pv.w > bv) bv = pv.w;
        v[i] = bv; id[i] = a;
    }
    for (int it = 0; it < NGAMMA; ++it) {
        float bv = v[0]; int bi = id[0];
#pragma unroll
        for (int i = 1; i < 16; ++i)
            if (v[i] > bv || (v[i] == bv && id[i] < bi)) { bv = v[i]; bi = id[i]; }
#pragma unroll
        for (int off = 1; off < 64; off <<= 1) {
            const float ov = __shfl_xor(bv, off);
            const int   oi = __shfl_xor(bi, off);
            if (ov > bv || (ov == bv && oi < bi)) { bv = ov; bi = oi; }
        }
        if (lane == 0) {
            cval[blockIdx.x * NGAMMA + it] = bv;
            cidx[blockIdx.x * NGAMMA + it] = bi;
        }
#pragma unroll
        for (int i = 0; i < 16; ++i) if (id[i] == bi) v[i] = -1e30f;
    }
}

// ---- Phase 2b: wave-level merge 1280 -> top-20 -> best-j -> loss + avg ----
__global__ __launch_bounds__(256) void fm_final(
    const float* __restrict__ cval, const int* __restrict__ cidx,
    const float* __restrict__ pval, const int* __restrict__ pidx,
    const float* __restrict__ z, float* __restrict__ out)
{
    __shared__ int sel[NGAMMA];
    __shared__ int selj[NGAMMA];
    __shared__ float red[4];

    const int t = threadIdx.x;
    const int lane = t & 63, w = t >> 6;
    float ssum = 0.f;

    if (w == 0) {
        float v[20]; int id[20];
#pragma unroll
        for (int i = 0; i < 20; ++i) {
            const int e = i * 64 + lane;
            v[i] = cval[e]; id[i] = cidx[e];
        }
        for (int it = 0; it < NGAMMA; ++it) {
            float bv = v[0]; int bi = id[0];
#pragma unroll
            for (int i = 1; i < 20; ++i)
                if (v[i] > bv || (v[i] == bv && id[i] < bi)) { bv = v[i]; bi = id[i]; }
#pragma unroll
            for (int off = 1; off < 64; off <<= 1) {
                const float ov = __shfl_xor(bv, off);
                const int   oi = __shfl_xor(bi, off);
                if (ov > bv || (ov == bv && oi < bi)) { bv = ov; bi = oi; }
            }
            if (lane == 0) sel[it] = bi;
            ssum += bv;
#pragma unroll
            for (int i = 0; i < 20; ++i) if (id[i] == bi) v[i] = -1e30f;
        }
        // best-j for the 20 selected anchors (argmax over 4 partials)
        if (lane < NGAMMA) {
            const int a = sel[lane];   // written by lane0; same-wave ordered
            const float4 pv = ((const float4*)pval)[a];
            float bv = pv.x; int bc = 0;       // ascending c = ascending q-block
            if (pv.y > bv) { bv = pv.y; bc = 1; }
            if (pv.z > bv) { bv = pv.z; bc = 2; }
            if (pv.w > bv) { bv = pv.w; bc = 3; }
            selj[lane] = ((a >> 9) << 9) + pidx[(size_t)a * 4 + bc];
        }
    }
    __syncthreads();

    // loss = 25 * mean((z1 - z2)^2) over 20 x 384 (exact fp32 z)
    float acc = 0.f;
    for (int pr = 0; pr < NGAMMA; ++pr) {
        const int a = sel[pr];
        const int j = selj[pr];
        const float* za = z + (size_t)a * ND;
        const float* zj = z + (size_t)j * ND;
        for (int d = t; d < ND; d += 256) {
            const float df = za[d] - zj[d];
            acc = fmaf(df, df, acc);
        }
    }
#pragma unroll
    for (int off = 1; off < 64; off <<= 1) acc += __shfl_xor(acc, off);
    if (lane == 0) red[w] = acc;
    __syncthreads();
    if (t == 0) {
        const float tot = red[0] + red[1] + red[2] + red[3];
        out[0] = 25.0f * tot / (float)(NGAMMA * ND);
        out[1] = ssum / (float)NGAMMA;   // t==0 is lane0 of wave0: has ssum
    }
}

extern "C" void kernel_launch(void* const* d_in, const int* in_sizes, int n_in,
                              void* d_out, int out_size, void* d_ws, size_t ws_size,
                              hipStream_t stream)
{
    const float* z    = (const float*)d_in[0];
    const int*   view = (const int*)d_in[1];
    float*       out  = (float*)d_out;
    char* ws = (char*)d_ws;

    // layout: zt 48MB | pval 1MB | pidx 1MB | cval | cidx
    const size_t zt_off   = 0;
    const size_t pval_off = (size_t)NB * NP * ND * 2;
    const size_t pidx_off = pval_off + (size_t)NB * NP * 4 * 4;
    const size_t cval_off = pidx_off + (size_t)NB * NP * 4 * 4;
    const size_t cidx_off = cval_off + 64 * NGAMMA * 4;

    unsigned short* zt = (unsigned short*)(ws + zt_off);
    float* pval = (float*)(ws + pval_off);
    int*   pidx = (int*)(ws + pidx_off);
    float* cval = (float*)(ws + cval_off);
    int*   cidx = (int*)(ws + cidx_off);

    fm_convert<<<NB * NKS * 4, 256, 0, stream>>>(z, zt);
    fm_gemm<<<NB * 10, 256, 0, stream>>>(zt, view, pval, pidx);
    fm_topk_local<<<(NB * NP) / 1024, 64, 0, stream>>>(pval, cval, cidx);
    fm_final<<<1, 256, 0, stream>>>(cval, cidx, pval, pidx, z, out);
}